// Round 9
// baseline (255.052 us; speedup 1.0000x reference)
//
#include <hip/hip_runtime.h>
#include <stdint.h>

#define N_NODES 207
#define N_EDGES 1722
#define N_SLOTS 288
#define L_DIM   64
#define EB_STRIDE 4096   // padded CSR capacity: max 3444 + 3*207 = 4065 <= 4096

typedef __attribute__((ext_vector_type(2))) float f32x2;   // -> v_pk_fma_f32

// Round-to-nearest f32 -> bf16, returned as f32 bit pattern with low 16 zeroed
__device__ __forceinline__ unsigned int f2bf_rtn_bits_hi(float f) {
    unsigned int u = __float_as_uint(f);
    unsigned int r = u + 0x7FFFu + ((u >> 16) & 1u);
    return r & 0xFFFF0000u;
}

// ---------------------------------------------------------------------------
// K1: build PADDED CSR from the batch-invariant edge list.
//   rs_p[208] ints (each node's segment padded to a multiple of 4)
//   csr_p[4096] uints = (edge_id<<8)|neighbor, pad slots = 0xFFFFFFFF
// Self-loop edges (i==j) appear twice in node i's list -> A[i,i] += 2w (matches ref).
// ---------------------------------------------------------------------------
__global__ __launch_bounds__(256) void build_csr_kernel(
    const int* __restrict__ edge_i, const int* __restrict__ edge_j,
    int* __restrict__ rs_p, unsigned int* __restrict__ csr_p) {
    __shared__ int cnt[N_NODES];
    __shared__ int rs[N_NODES + 1];
    const int tid = threadIdx.x;

    for (int n = tid; n < N_NODES; n += 256) cnt[n] = 0;
    __syncthreads();
    for (int e = tid; e < N_EDGES; e += 256) {
        atomicAdd(&cnt[edge_i[e]], 1);
        atomicAdd(&cnt[edge_j[e]], 1);
    }
    __syncthreads();
    if (tid == 0) {
        int acc = 0;
        for (int n = 0; n < N_NODES; ++n) { rs[n] = acc; acc += (cnt[n] + 3) & ~3; }
        rs[N_NODES] = acc;   // <= 4065
    }
    __syncthreads();
    for (int n = tid; n <= N_NODES; n += 256) rs_p[n] = rs[n];
    for (int k = tid; k < EB_STRIDE; k += 256) csr_p[k] = 0xFFFFFFFFu;  // pads
    for (int n = tid; n < N_NODES; n += 256) cnt[n] = rs[n];
    __syncthreads();   // orders the global pad-fill before the scatter (same block)
    for (int e = tid; e < N_EDGES; e += 256) {
        const unsigned int i = edge_i[e], j = edge_j[e];
        const unsigned int ep = ((unsigned int)e) << 8;
        int p = atomicAdd(&cnt[i], 1);
        csr_p[p] = ep | j;
        int q = atomicAdd(&cnt[j], 1);
        csr_p[q] = ep | i;
    }
}

// ---------------------------------------------------------------------------
// K1b: per slot, precompute
//   coefbias[s][n] = {1 + wsl + deg, bias}                  (float2)
//   eb32p[s][k]    = (w bf16 in HIGH16) | (nb*256 in LOW16) (u32; pads = 0)
// nb*256 = byte offset of node row in the FP32 LDS x array (<= 52,736, 16 bits).
// K2 streams eb32p from GLOBAL (L2-hot, 16 KB/slot); LDS pipe reserved for the
// x-gather.
// ---------------------------------------------------------------------------
__global__ __launch_bounds__(256) void coef_eb_kernel(
    const float* __restrict__ weight_diff, const float* __restrict__ bias_diffusion,
    const float* __restrict__ weight_self_loop,
    const int* __restrict__ rs_p, const unsigned int* __restrict__ csr_p,
    float2* __restrict__ coefbias, unsigned int* __restrict__ eb32p) {
    __shared__ float wrow[N_EDGES];
    const int s = blockIdx.x;
    for (int e = threadIdx.x; e < N_EDGES; e += 256)
        wrow[e] = weight_diff[(size_t)s * N_EDGES + e];
    __syncthreads();

    if (eb32p != nullptr) {
        const int EP = rs_p[N_NODES];
        unsigned int* ebs = eb32p + (size_t)s * EB_STRIDE;
        for (int k = threadIdx.x; k < EB_STRIDE; k += 256) {
            unsigned int v = 0u;
            if (k < EP) {
                const unsigned int c = csr_p[k];
                if (c != 0xFFFFFFFFu)
                    v = f2bf_rtn_bits_hi(wrow[c >> 8]) | ((c & 255u) << 8);
            }
            ebs[k] = v;
        }
    }

    const int n = threadIdx.x;
    if (n < N_NODES) {
        float d = 0.f;
        const int e0 = rs_p[n], e1 = rs_p[n + 1];
        for (int k = e0; k < e1; ++k) {
            const unsigned int c = csr_p[k];
            if (c != 0xFFFFFFFFu) d += wrow[c >> 8];
        }
        coefbias[s * N_NODES + n] = make_float2(
            1.f + weight_self_loop[s * N_NODES + n] + d,
            bias_diffusion[s * N_NODES + n]);
    }
}

// ---------------------------------------------------------------------------
// K2 (quad-edge, fp32-LDS): one block (512 thr = 8 waves) per batch element.
//   out[n,l] = coef*x[n,l] + bias - sum_k w[k]*x[nb[k],l]
// Round-8 post-mortem: kernel is issue/latency bound, not pipe-bound -> cut
// wave-instructions per 4-edge group from ~14 to ~9:
//  - x stored FP32 in LDS (row = 256 B): kills the 4 bf16-unpack shifts per
//    group AND the f32->bf16 staging pack (plain float4 copy)
//  - gather widened to ds_read_b128 (4 fp32 l-values; 16 lanes span the full
//    256 B row -> 2-way banking, free)
//  - 4 fma pair into 2 v_pk_fma_f32 via f32x2 vector ops
//  - edge stream from global (L2-hot), quad h = lane>>4 handles edge k+h
// LDS = 52,992 + 828 = 53.8 KB -> 3 blocks/CU, 24 waves/CU.
// ---------------------------------------------------------------------------
__global__ __launch_bounds__(512, 6) void diffusion_quad32_kernel(
    const float* __restrict__ inputs,          // (B, 2, 207, 64)
    const int*   __restrict__ ind,             // (B,)
    const int*   __restrict__ rs_p_g,          // (208,) padded
    const unsigned int* __restrict__ eb32p,    // (288, EB_STRIDE)
    const float2* __restrict__ coefbias,       // (288, 207)
    float* __restrict__ out) {                 // (B, 207, 64)
    __shared__ float        xs[N_NODES * L_DIM];     // 52,992 B (fp32, row = 256 B)
    __shared__ unsigned int rsp[N_NODES];            //    828 B: e0 | e1<<16

    const int b    = blockIdx.x;
    const int tid  = threadIdx.x;
    const int slot = ind[b];                   // uniform -> SGPR

    const float* xb = inputs + (size_t)b * (2 * N_NODES * L_DIM);  // channel 0

    // Stage x fp32 -> LDS: plain float4 copy (no conversion VALU)
    const float4* xb4 = (const float4*)xb;
    float4* xs4 = (float4*)xs;
    for (int k = tid; k < (N_NODES * L_DIM) / 4; k += 512) xs4[k] = xb4[k];
    for (int n = tid; n < N_NODES; n += 512)
        rsp[n] = (unsigned int)rs_p_g[n] | ((unsigned int)rs_p_g[n + 1] << 16);
    __syncthreads();

    const int lane = tid & 63;
    const int wv   = tid >> 6;                 // 8 waves
    const int h    = lane >> 4;                // quad 0..3 -> edge k+h
    const unsigned int li16 = (unsigned int)((lane & 15) << 4);  // byte off: l=4i
    const unsigned int* ebs = eb32p + (size_t)slot * EB_STRIDE + h;
    const float2* cbs = coefbias + (size_t)slot * N_NODES;
    float* ob = out + (size_t)b * (N_NODES * L_DIM);
    const char* xsb = (const char*)xs;

    for (int n = wv; n < N_NODES; n += 8) {
        const unsigned int rr = rsp[n];        // one ds_read_b32 per node
        const int e0 = (int)(rr & 0xFFFFu);
        const int e1 = (int)(rr >> 16);
        f32x2 sA = {0.f, 0.f}, sB = {0.f, 0.f};
        #pragma unroll 2
        for (int k = e0; k < e1; k += 4) {     // (e1-e0) is a multiple of 4
            const unsigned int p = ebs[k];                     // global, L2-hot
            const float w = __uint_as_float(p & 0xFFFF0000u);  // bf16 weight bits
            const unsigned int off = (p & 0xFFFFu) | li16;     // v_and_or_b32
            const float4 xv = *(const float4*)(xsb + off);     // ds_read_b128
            const f32x2 w2 = {w, w};
            const f32x2 xlo = {xv.x, xv.y};
            const f32x2 xhi = {xv.z, xv.w};
            sA += w2 * xlo;                                    // v_pk_fma_f32
            sB += w2 * xhi;
        }
        float s0 = sA.x, s1 = sA.y, s2 = sB.x, s3 = sB.y;
        // combine the 4 quads' partial sums (each quad summed edges k+h)
        s0 += __shfl_xor(s0, 16); s1 += __shfl_xor(s1, 16);
        s2 += __shfl_xor(s2, 16); s3 += __shfl_xor(s3, 16);
        s0 += __shfl_xor(s0, 32); s1 += __shfl_xor(s1, 32);
        s2 += __shfl_xor(s2, 32); s3 += __shfl_xor(s3, 32);
        if (lane < 16) {                       // 16 lanes x float4 = exact 256B row
            const float2 cb = cbs[n];
            const int o4 = (n << 6) + (lane << 2);
            const float4 xg = *(const float4*)(xs + o4);   // fp32 self term (LDS)
            float4 o;
            o.x = fmaf(cb.x, xg.x, cb.y) - s0;
            o.y = fmaf(cb.x, xg.y, cb.y) - s1;
            o.z = fmaf(cb.x, xg.z, cb.y) - s2;
            o.w = fmaf(cb.x, xg.w, cb.y) - s3;
            *(float4*)(ob + o4) = o;
        }
    }
}

// ---------------------------------------------------------------------------
// K2 (fallback, baseline-style, padded-CSR aware): used only if ws too small
// for the eb32p table. Per-block weight gather + u16 LDS reads.
// ---------------------------------------------------------------------------
__global__ __launch_bounds__(512, 8) void diffusion_gcn_fallback(
    const float* __restrict__ inputs,
    const float* __restrict__ weight_diff,
    const int*   __restrict__ ind,
    const int*   __restrict__ rs_p_g,
    const unsigned int* __restrict__ csr_p,
    const float2* __restrict__ coefbias,
    float* __restrict__ out) {
    __shared__ unsigned short xsh[N_NODES * L_DIM];
    __shared__ unsigned int   wnb[EB_STRIDE];
    __shared__ unsigned short rs[N_NODES + 1];

    const int b    = blockIdx.x;
    const int tid  = threadIdx.x;
    const int slot = ind[b];

    const float* xb = inputs + (size_t)b * (2 * N_NODES * L_DIM);

    const float4* xb4 = (const float4*)xb;
    for (int k = tid; k < (N_NODES * L_DIM) / 4; k += 512) {
        const float4 v = xb4[k];
        const unsigned int lo = (f2bf_rtn_bits_hi(v.x) >> 16) | f2bf_rtn_bits_hi(v.y);
        const unsigned int hi = (f2bf_rtn_bits_hi(v.z) >> 16) | f2bf_rtn_bits_hi(v.w);
        ((uint2*)xsh)[k] = make_uint2(lo, hi);
    }
    const int EP = rs_p_g[N_NODES];
    const float* wrow = weight_diff + (size_t)slot * N_EDGES;
    for (int k = tid; k < EP; k += 512) {
        const unsigned int c = csr_p[k];
        wnb[k] = (c == 0xFFFFFFFFu) ? 0u
                                    : (f2bf_rtn_bits_hi(wrow[c >> 8]) | (c & 255u));
    }
    for (int n = tid; n <= N_NODES; n += 512) rs[n] = (unsigned short)rs_p_g[n];
    __syncthreads();

    const int lane = tid & 63;
    const int wv   = tid >> 6;
    float* ob = out + (size_t)b * (N_NODES * L_DIM);

    for (int n = wv; n < N_NODES; n += 8) {
        const int e0 = rs[n], e1 = rs[n + 1];
        float s = 0.f;
        #pragma unroll 4
        for (int k = e0; k < e1; ++k) {
            const unsigned int p = wnb[k];
            const float w  = __uint_as_float(p & 0xFFFF0000u);
            const float xv = __uint_as_float(
                (unsigned int)xsh[(p & 255u) * L_DIM + lane] << 16);
            s = fmaf(w, xv, s);
        }
        const float2 cb = coefbias[slot * N_NODES + n];
        const float  xg = xb[n * L_DIM + lane];
        ob[n * L_DIM + lane] = fmaf(cb.x, xg, cb.y) - s;
    }
}

extern "C" void kernel_launch(void* const* d_in, const int* in_sizes, int n_in,
                              void* d_out, int out_size, void* d_ws, size_t ws_size,
                              hipStream_t stream) {
    const float* inputs           = (const float*)d_in[0];
    const float* weight_diff      = (const float*)d_in[1];
    const float* bias_diffusion   = (const float*)d_in[2];
    const float* weight_self_loop = (const float*)d_in[3];
    const int*   ind              = (const int*)d_in[4];
    const int*   edge_i           = (const int*)d_in[5];
    const int*   edge_j           = (const int*)d_in[6];
    float* out = (float*)d_out;

    const int B = in_sizes[4];                 // 1024

    // ws layout
    char* ws = (char*)d_ws;
    int*          rs_p     = (int*)ws;                           //      1,024 B
    unsigned int* csr_p    = (unsigned int*)(ws + 1024);         //     16,384 B
    float2*       coefbias = (float2*)(ws + 17408);              //    476,928 B
    unsigned int* eb32p    = (unsigned int*)(ws + 494336);       //  4,718,592 B
    const size_t WS_FULL = 494336 + (size_t)N_SLOTS * EB_STRIDE * sizeof(unsigned int);

    const bool full = (d_ws != nullptr) && (ws_size >= WS_FULL);

    build_csr_kernel<<<1, 256, 0, stream>>>(edge_i, edge_j, rs_p, csr_p);
    coef_eb_kernel<<<N_SLOTS, 256, 0, stream>>>(
        weight_diff, bias_diffusion, weight_self_loop, rs_p, csr_p,
        coefbias, full ? eb32p : nullptr);
    if (full) {
        diffusion_quad32_kernel<<<B, 512, 0, stream>>>(
            inputs, ind, rs_p, eb32p, coefbias, out);
    } else {
        diffusion_gcn_fallback<<<B, 512, 0, stream>>>(
            inputs, weight_diff, ind, rs_p, csr_p, coefbias, out);
    }
}

// Round 10
// 239.855 us; speedup vs baseline: 1.0634x; 1.0634x over previous
//
#include <hip/hip_runtime.h>
#include <stdint.h>

#define N_NODES 207
#define N_EDGES 1722
#define N_SLOTS 288
#define L_DIM   64
#define EB_STRIDE 8192   // padded CSR capacity: max 3444 + 7*207 = 4893 <= 8192

// Round-to-nearest f32 -> bf16, returned as f32 bit pattern with low 16 zeroed
__device__ __forceinline__ unsigned int f2bf_rtn_bits_hi(float f) {
    unsigned int u = __float_as_uint(f);
    unsigned int r = u + 0x7FFFu + ((u >> 16) & 1u);
    return r & 0xFFFF0000u;
}

__device__ __forceinline__ float uf(unsigned int u) { return __uint_as_float(u); }

// ---------------------------------------------------------------------------
// K1: build PADDED CSR from the batch-invariant edge list.
//   rs_p[208] ints (each node's segment padded to a multiple of 8)
//   csr_p[EB_STRIDE] uints = (edge_id<<8)|neighbor, pad slots = 0xFFFFFFFF
// Self-loop edges (i==j) appear twice in node i's list -> A[i,i] += 2w (matches ref).
// ---------------------------------------------------------------------------
__global__ __launch_bounds__(256) void build_csr_kernel(
    const int* __restrict__ edge_i, const int* __restrict__ edge_j,
    int* __restrict__ rs_p, unsigned int* __restrict__ csr_p) {
    __shared__ int cnt[N_NODES];
    __shared__ int rs[N_NODES + 1];
    const int tid = threadIdx.x;

    for (int n = tid; n < N_NODES; n += 256) cnt[n] = 0;
    __syncthreads();
    for (int e = tid; e < N_EDGES; e += 256) {
        atomicAdd(&cnt[edge_i[e]], 1);
        atomicAdd(&cnt[edge_j[e]], 1);
    }
    __syncthreads();
    if (tid == 0) {
        int acc = 0;
        for (int n = 0; n < N_NODES; ++n) { rs[n] = acc; acc += (cnt[n] + 7) & ~7; }
        rs[N_NODES] = acc;   // <= 4893
    }
    __syncthreads();
    for (int n = tid; n <= N_NODES; n += 256) rs_p[n] = rs[n];
    for (int k = tid; k < EB_STRIDE; k += 256) csr_p[k] = 0xFFFFFFFFu;  // pads
    for (int n = tid; n < N_NODES; n += 256) cnt[n] = rs[n];
    __syncthreads();   // orders the global pad-fill before the scatter (same block)
    for (int e = tid; e < N_EDGES; e += 256) {
        const unsigned int i = edge_i[e], j = edge_j[e];
        const unsigned int ep = ((unsigned int)e) << 8;
        int p = atomicAdd(&cnt[i], 1);
        csr_p[p] = ep | j;
        int q = atomicAdd(&cnt[j], 1);
        csr_p[q] = ep | i;
    }
}

// ---------------------------------------------------------------------------
// K1b: per slot, precompute
//   coefbias[s][n] = {1 + wsl + deg, bias}                  (float2)
//   eb32p[s][k]    = (w bf16 in HIGH16) | (nb*128 in LOW16) (u32; pads = 0)
// nb*128 = byte offset of node row in the bf16 LDS x array (<= 26,368).
// K2 streams eb32p from GLOBAL (L2-hot, 20 KB/slot); LDS pipe reserved for the
// x-gather.
// ---------------------------------------------------------------------------
__global__ __launch_bounds__(256) void coef_eb_kernel(
    const float* __restrict__ weight_diff, const float* __restrict__ bias_diffusion,
    const float* __restrict__ weight_self_loop,
    const int* __restrict__ rs_p, const unsigned int* __restrict__ csr_p,
    float2* __restrict__ coefbias, unsigned int* __restrict__ eb32p) {
    __shared__ float wrow[N_EDGES];
    const int s = blockIdx.x;
    for (int e = threadIdx.x; e < N_EDGES; e += 256)
        wrow[e] = weight_diff[(size_t)s * N_EDGES + e];
    __syncthreads();

    if (eb32p != nullptr) {
        const int EP = rs_p[N_NODES];
        unsigned int* ebs = eb32p + (size_t)s * EB_STRIDE;
        for (int k = threadIdx.x; k < EB_STRIDE; k += 256) {
            unsigned int v = 0u;
            if (k < EP) {
                const unsigned int c = csr_p[k];
                if (c != 0xFFFFFFFFu)
                    v = f2bf_rtn_bits_hi(wrow[c >> 8]) | ((c & 255u) << 7);
            }
            ebs[k] = v;
        }
    }

    const int n = threadIdx.x;
    if (n < N_NODES) {
        float d = 0.f;
        const int e0 = rs_p[n], e1 = rs_p[n + 1];
        for (int k = e0; k < e1; ++k) {
            const unsigned int c = csr_p[k];
            if (c != 0xFFFFFFFFu) d += wrow[c >> 8];
        }
        coefbias[s * N_NODES + n] = make_float2(
            1.f + weight_self_loop[s * N_NODES + n] + d,
            bias_diffusion[s * N_NODES + n]);
    }
}

// ---------------------------------------------------------------------------
// K2 (octo-edge): one block (512 thr = 8 waves) per batch element.
//   out[n,l] = coef*x[n,l] + bias - sum_k w[k]*x[nb[k],l]
// Rounds 4/8/9 post-mortem: kernel is DEPENDENT-LOAD LATENCY bound at max
// occupancy (same 70us for 8x different LDS-pipe load; regresses when
// occupancy drops). Fix: widen memory-level parallelism per wave at the SAME
// resource mix as r8 (bf16 LDS x, 27.6KB, 4 blocks/CU = wave cap):
//  - node segments padded to multiples of 8 -> inner loop handles 8 edges
//    (two 4-edge groups, independent accumulator sets, loads issued together)
//  - #pragma unroll 2 -> 4 groups (16 edges) of load chains in flight
//  - quad h = lane>>4 handles edges k+h / k+4+h; lane covers l=4i..4i+3
// ---------------------------------------------------------------------------
__global__ __launch_bounds__(512, 8) void diffusion_octo_kernel(
    const float* __restrict__ inputs,          // (B, 2, 207, 64)
    const int*   __restrict__ ind,             // (B,)
    const int*   __restrict__ rs_p_g,          // (208,) padded
    const unsigned int* __restrict__ eb32p,    // (288, EB_STRIDE)
    const float2* __restrict__ coefbias,       // (288, 207)
    float* __restrict__ out) {                 // (B, 207, 64)
    __shared__ unsigned short xs[N_NODES * L_DIM];   // 26,496 B (bf16, row = 128 B)
    __shared__ unsigned int   rsp[N_NODES];          //    828 B: e0 | e1<<16

    const int b    = blockIdx.x;
    const int tid  = threadIdx.x;
    const int slot = ind[b];                   // uniform -> SGPR

    const float* xb = inputs + (size_t)b * (2 * N_NODES * L_DIM);  // channel 0

    // Stage x (fp32 global, float4) -> bf16 LDS (linear rows)
    const float4* xb4 = (const float4*)xb;
    for (int k = tid; k < (N_NODES * L_DIM) / 4; k += 512) {
        const float4 v = xb4[k];
        const unsigned int lo = (f2bf_rtn_bits_hi(v.x) >> 16) | f2bf_rtn_bits_hi(v.y);
        const unsigned int hi = (f2bf_rtn_bits_hi(v.z) >> 16) | f2bf_rtn_bits_hi(v.w);
        ((uint2*)xs)[k] = make_uint2(lo, hi);
    }
    for (int n = tid; n < N_NODES; n += 512)
        rsp[n] = (unsigned int)rs_p_g[n] | ((unsigned int)rs_p_g[n + 1] << 16);
    __syncthreads();

    const int lane = tid & 63;
    const int wv   = tid >> 6;                 // 8 waves
    const int h    = lane >> 4;                // quad 0..3
    const unsigned int li8 = (unsigned int)((lane & 15) << 3);  // byte off: l=4i
    const unsigned int* ebs = eb32p + (size_t)slot * EB_STRIDE;
    const float2* cbs = coefbias + (size_t)slot * N_NODES;
    float* ob = out + (size_t)b * (N_NODES * L_DIM);
    const char* xsb = (const char*)xs;

    for (int n = wv; n < N_NODES; n += 8) {
        const unsigned int rr = rsp[n];        // one ds_read_b32 per node
        const int e0 = (int)(rr & 0xFFFFu);
        const int e1 = (int)(rr >> 16);
        float s0 = 0.f, s1 = 0.f, s2 = 0.f, s3 = 0.f;   // chain A accumulators
        float t0 = 0.f, t1 = 0.f, t2 = 0.f, t3 = 0.f;   // chain B accumulators
        #pragma unroll 2
        for (int k = e0; k < e1; k += 8) {     // (e1-e0) is a multiple of 8
            const unsigned int pA = ebs[k + h];          // global, L2-hot
            const unsigned int pB = ebs[k + 4 + h];      // independent chain
            const unsigned int offA = (pA & 0xFFFFu) | li8;
            const unsigned int offB = (pB & 0xFFFFu) | li8;
            const uint2 xvA = *(const uint2*)(xsb + offA);   // ds_read_b64
            const uint2 xvB = *(const uint2*)(xsb + offB);   // ds_read_b64
            const unsigned int wA = pA & 0xFFFF0000u;
            const unsigned int wB = pB & 0xFFFF0000u;
            s0 = fmaf(uf(wA), uf(xvA.x << 16),        s0);
            s1 = fmaf(uf(wA), uf(xvA.x & 0xFFFF0000u), s1);
            s2 = fmaf(uf(wA), uf(xvA.y << 16),        s2);
            s3 = fmaf(uf(wA), uf(xvA.y & 0xFFFF0000u), s3);
            t0 = fmaf(uf(wB), uf(xvB.x << 16),        t0);
            t1 = fmaf(uf(wB), uf(xvB.x & 0xFFFF0000u), t1);
            t2 = fmaf(uf(wB), uf(xvB.y << 16),        t2);
            t3 = fmaf(uf(wB), uf(xvB.y & 0xFFFF0000u), t3);
        }
        s0 += t0; s1 += t1; s2 += t2; s3 += t3;
        // combine the 4 quads' partial sums (each quad summed edges k+h, k+4+h)
        s0 += __shfl_xor(s0, 16); s1 += __shfl_xor(s1, 16);
        s2 += __shfl_xor(s2, 16); s3 += __shfl_xor(s3, 16);
        s0 += __shfl_xor(s0, 32); s1 += __shfl_xor(s1, 32);
        s2 += __shfl_xor(s2, 32); s3 += __shfl_xor(s3, 32);
        if (lane < 16) {                       // 16 lanes x float4 = exact 256B row
            const float2 cb = cbs[n];
            const int o4 = (n << 6) + (lane << 2);
            const float4 xg = *(const float4*)(xb + o4);   // fp32 self term
            float4 o;
            o.x = fmaf(cb.x, xg.x, cb.y) - s0;
            o.y = fmaf(cb.x, xg.y, cb.y) - s1;
            o.z = fmaf(cb.x, xg.z, cb.y) - s2;
            o.w = fmaf(cb.x, xg.w, cb.y) - s3;
            *(float4*)(ob + o4) = o;
        }
    }
}

// ---------------------------------------------------------------------------
// K2 (fallback, baseline-style, padded-CSR aware): used only if ws too small
// for the eb32p table. Per-block weight gather + u16 LDS reads.
// ---------------------------------------------------------------------------
__global__ __launch_bounds__(512, 4) void diffusion_gcn_fallback(
    const float* __restrict__ inputs,
    const float* __restrict__ weight_diff,
    const int*   __restrict__ ind,
    const int*   __restrict__ rs_p_g,
    const unsigned int* __restrict__ csr_p,
    const float2* __restrict__ coefbias,
    float* __restrict__ out) {
    __shared__ unsigned short xsh[N_NODES * L_DIM];
    __shared__ unsigned int   wnb[EB_STRIDE];          // 32 KB (EP <= 4893 used)
    __shared__ unsigned short rs[N_NODES + 1];

    const int b    = blockIdx.x;
    const int tid  = threadIdx.x;
    const int slot = ind[b];

    const float* xb = inputs + (size_t)b * (2 * N_NODES * L_DIM);

    const float4* xb4 = (const float4*)xb;
    for (int k = tid; k < (N_NODES * L_DIM) / 4; k += 512) {
        const float4 v = xb4[k];
        const unsigned int lo = (f2bf_rtn_bits_hi(v.x) >> 16) | f2bf_rtn_bits_hi(v.y);
        const unsigned int hi = (f2bf_rtn_bits_hi(v.z) >> 16) | f2bf_rtn_bits_hi(v.w);
        ((uint2*)xsh)[k] = make_uint2(lo, hi);
    }
    const int EP = rs_p_g[N_NODES];
    const float* wrow = weight_diff + (size_t)slot * N_EDGES;
    for (int k = tid; k < EP; k += 512) {
        const unsigned int c = csr_p[k];
        wnb[k] = (c == 0xFFFFFFFFu) ? 0u
                                    : (f2bf_rtn_bits_hi(wrow[c >> 8]) | (c & 255u));
    }
    for (int n = tid; n <= N_NODES; n += 512) rs[n] = (unsigned short)rs_p_g[n];
    __syncthreads();

    const int lane = tid & 63;
    const int wv   = tid >> 6;
    float* ob = out + (size_t)b * (N_NODES * L_DIM);

    for (int n = wv; n < N_NODES; n += 8) {
        const int e0 = rs[n], e1 = rs[n + 1];
        float s = 0.f;
        #pragma unroll 4
        for (int k = e0; k < e1; ++k) {
            const unsigned int p = wnb[k];
            const float w  = __uint_as_float(p & 0xFFFF0000u);
            const float xv = __uint_as_float(
                (unsigned int)xsh[(p & 255u) * L_DIM + lane] << 16);
            s = fmaf(w, xv, s);
        }
        const float2 cb = coefbias[slot * N_NODES + n];
        const float  xg = xb[n * L_DIM + lane];
        ob[n * L_DIM + lane] = fmaf(cb.x, xg, cb.y) - s;
    }
}

extern "C" void kernel_launch(void* const* d_in, const int* in_sizes, int n_in,
                              void* d_out, int out_size, void* d_ws, size_t ws_size,
                              hipStream_t stream) {
    const float* inputs           = (const float*)d_in[0];
    const float* weight_diff      = (const float*)d_in[1];
    const float* bias_diffusion   = (const float*)d_in[2];
    const float* weight_self_loop = (const float*)d_in[3];
    const int*   ind              = (const int*)d_in[4];
    const int*   edge_i           = (const int*)d_in[5];
    const int*   edge_j           = (const int*)d_in[6];
    float* out = (float*)d_out;

    const int B = in_sizes[4];                 // 1024

    // ws layout
    char* ws = (char*)d_ws;
    int*          rs_p     = (int*)ws;                           //      1,024 B
    unsigned int* csr_p    = (unsigned int*)(ws + 1024);         //     32,768 B
    float2*       coefbias = (float2*)(ws + 33792);              //    476,928 B
    unsigned int* eb32p    = (unsigned int*)(ws + 510720);       //  9,437,184 B
    const size_t WS_FULL = 510720 + (size_t)N_SLOTS * EB_STRIDE * sizeof(unsigned int);

    const bool full = (d_ws != nullptr) && (ws_size >= WS_FULL);

    build_csr_kernel<<<1, 256, 0, stream>>>(edge_i, edge_j, rs_p, csr_p);
    coef_eb_kernel<<<N_SLOTS, 256, 0, stream>>>(
        weight_diff, bias_diffusion, weight_self_loop, rs_p, csr_p,
        coefbias, full ? eb32p : nullptr);
    if (full) {
        diffusion_octo_kernel<<<B, 512, 0, stream>>>(
            inputs, ind, rs_p, eb32p, coefbias, out);
    } else {
        diffusion_gcn_fallback<<<B, 512, 0, stream>>>(
            inputs, weight_diff, ind, rs_p, csr_p, coefbias, out);
    }
}

// Round 11
// 238.732 us; speedup vs baseline: 1.0684x; 1.0047x over previous
//
#include <hip/hip_runtime.h>
#include <stdint.h>

#define N_NODES 207
#define N_EDGES 1722
#define N_SLOTS 288
#define L_DIM   64
#define EB_STRIDE 4096   // padded CSR capacity: max 3444 + 3*207 = 4065 <= 4096

// Round-to-nearest f32 -> bf16, returned as f32 bit pattern with low 16 zeroed
__device__ __forceinline__ unsigned int f2bf_rtn_bits_hi(float f) {
    unsigned int u = __float_as_uint(f);
    unsigned int r = u + 0x7FFFu + ((u >> 16) & 1u);
    return r & 0xFFFF0000u;
}

__device__ __forceinline__ float uf(unsigned int u) { return __uint_as_float(u); }

// ---------------------------------------------------------------------------
// K1: build PADDED CSR from the batch-invariant edge list.
//   rs_p[208] ints (each node's segment padded to a multiple of 4)
//   csr_p[EB_STRIDE] uints = (edge_id<<8)|neighbor, pad slots = 0xFFFFFFFF
// Self-loop edges (i==j) appear twice in node i's list -> A[i,i] += 2w (matches ref).
// ---------------------------------------------------------------------------
__global__ __launch_bounds__(256) void build_csr_kernel(
    const int* __restrict__ edge_i, const int* __restrict__ edge_j,
    int* __restrict__ rs_p, unsigned int* __restrict__ csr_p) {
    __shared__ int cnt[N_NODES];
    __shared__ int rs[N_NODES + 1];
    const int tid = threadIdx.x;

    for (int n = tid; n < N_NODES; n += 256) cnt[n] = 0;
    __syncthreads();
    for (int e = tid; e < N_EDGES; e += 256) {
        atomicAdd(&cnt[edge_i[e]], 1);
        atomicAdd(&cnt[edge_j[e]], 1);
    }
    __syncthreads();
    if (tid == 0) {
        int acc = 0;
        for (int n = 0; n < N_NODES; ++n) { rs[n] = acc; acc += (cnt[n] + 3) & ~3; }
        rs[N_NODES] = acc;   // <= 4065
    }
    __syncthreads();
    for (int n = tid; n <= N_NODES; n += 256) rs_p[n] = rs[n];
    for (int k = tid; k < EB_STRIDE; k += 256) csr_p[k] = 0xFFFFFFFFu;  // pads
    for (int n = tid; n < N_NODES; n += 256) cnt[n] = rs[n];
    __syncthreads();   // orders the global pad-fill before the scatter (same block)
    for (int e = tid; e < N_EDGES; e += 256) {
        const unsigned int i = edge_i[e], j = edge_j[e];
        const unsigned int ep = ((unsigned int)e) << 8;
        int p = atomicAdd(&cnt[i], 1);
        csr_p[p] = ep | j;
        int q = atomicAdd(&cnt[j], 1);
        csr_p[q] = ep | i;
    }
}

// ---------------------------------------------------------------------------
// K1b: per slot, precompute
//   coefbias[s][n] = {1 + wsl + deg, bias}                  (float2)
//   eb32p[s][k]    = (w bf16 in HIGH16) | (nb*128 in LOW16) (u32; pads = 0)
// nb*128 = byte offset of node row in the bf16 LDS x array (<= 26,368).
// K2 streams eb32p from GLOBAL (L2-hot, 16 KB/slot); LDS pipe reserved for the
// x-gather.
// ---------------------------------------------------------------------------
__global__ __launch_bounds__(256) void coef_eb_kernel(
    const float* __restrict__ weight_diff, const float* __restrict__ bias_diffusion,
    const float* __restrict__ weight_self_loop,
    const int* __restrict__ rs_p, const unsigned int* __restrict__ csr_p,
    float2* __restrict__ coefbias, unsigned int* __restrict__ eb32p) {
    __shared__ float wrow[N_EDGES];
    const int s = blockIdx.x;
    for (int e = threadIdx.x; e < N_EDGES; e += 256)
        wrow[e] = weight_diff[(size_t)s * N_EDGES + e];
    __syncthreads();

    if (eb32p != nullptr) {
        const int EP = rs_p[N_NODES];
        unsigned int* ebs = eb32p + (size_t)s * EB_STRIDE;
        for (int k = threadIdx.x; k < EB_STRIDE; k += 256) {
            unsigned int v = 0u;
            if (k < EP) {
                const unsigned int c = csr_p[k];
                if (c != 0xFFFFFFFFu)
                    v = f2bf_rtn_bits_hi(wrow[c >> 8]) | ((c & 255u) << 7);
            }
            ebs[k] = v;
        }
    }

    const int n = threadIdx.x;
    if (n < N_NODES) {
        float d = 0.f;
        const int e0 = rs_p[n], e1 = rs_p[n + 1];
        for (int k = e0; k < e1; ++k) {
            const unsigned int c = csr_p[k];
            if (c != 0xFFFFFFFFu) d += wrow[c >> 8];
        }
        coefbias[s * N_NODES + n] = make_float2(
            1.f + weight_self_loop[s * N_NODES + n] + d,
            bias_diffusion[s * N_NODES + n]);
    }
}

// ---------------------------------------------------------------------------
// K2 (dual-node): one block (512 thr = 8 waves) per batch element.
//   out[n,l] = coef*x[n,l] + bias - sum_k w[k]*x[nb[k],l]
// r4/r8/r10 post-mortem: 3 different kernels pinned at 70us; within-node
// unrolling never engages (avg ~2.5 trips) -> dependent-load chains drain at
// every node boundary. Fix: process node PAIR (nA, nB=nA+8) per wave
// simultaneously -- two cursors, two accumulator sets, loads co-issued, loop
// to max(trips) with wave-uniform clamping (exhausted side re-reads its own
// segment start, weight masked to 0; pads are 0 anyway). Guarantees 2
// independent chains/iter (4 with unroll 2) regardless of degree.
// Epilogue pairs too: lanes 0-15 write row nA, 16-31 row nB (full 256B rows).
// LDS = 26,496 + 828 = 27.3 KB -> 4 blocks/CU (wave cap).
// ---------------------------------------------------------------------------
__global__ __launch_bounds__(512, 8) void diffusion_dual_kernel(
    const float* __restrict__ inputs,          // (B, 2, 207, 64)
    const int*   __restrict__ ind,             // (B,)
    const int*   __restrict__ rs_p_g,          // (208,) padded
    const unsigned int* __restrict__ eb32p,    // (288, EB_STRIDE)
    const float2* __restrict__ coefbias,       // (288, 207)
    float* __restrict__ out) {                 // (B, 207, 64)
    __shared__ unsigned short xs[N_NODES * L_DIM];   // 26,496 B (bf16, row = 128 B)
    __shared__ unsigned int   rsp[N_NODES];          //    828 B: e0 | e1<<16

    const int b    = blockIdx.x;
    const int tid  = threadIdx.x;
    const int slot = ind[b];                   // uniform -> SGPR

    const float* xb = inputs + (size_t)b * (2 * N_NODES * L_DIM);  // channel 0

    // Stage x (fp32 global, float4) -> bf16 LDS (linear rows)
    const float4* xb4 = (const float4*)xb;
    for (int k = tid; k < (N_NODES * L_DIM) / 4; k += 512) {
        const float4 v = xb4[k];
        const unsigned int lo = (f2bf_rtn_bits_hi(v.x) >> 16) | f2bf_rtn_bits_hi(v.y);
        const unsigned int hi = (f2bf_rtn_bits_hi(v.z) >> 16) | f2bf_rtn_bits_hi(v.w);
        ((uint2*)xs)[k] = make_uint2(lo, hi);
    }
    for (int n = tid; n < N_NODES; n += 512)
        rsp[n] = (unsigned int)rs_p_g[n] | ((unsigned int)rs_p_g[n + 1] << 16);
    __syncthreads();

    const int lane = tid & 63;
    const int wv   = tid >> 6;                 // 8 waves
    const int h    = lane >> 4;                // quad 0..3 -> edge k+h
    const unsigned int li8 = (unsigned int)((lane & 15) << 3);  // byte off: l=4i
    const unsigned int* ebs = eb32p + (size_t)slot * EB_STRIDE;
    const float2* cbs = coefbias + (size_t)slot * N_NODES;
    float* ob = out + (size_t)b * (N_NODES * L_DIM);
    const char* xsb = (const char*)xs;

    for (int idx = 0; idx < 13; ++idx) {       // 13 pairs cover 26 node slots
        const int nA = wv + (idx << 4);        // < 207 always (max 199)
        const int nB = nA + 8;                 // may be 207 (wv=7, idx=12)
        const unsigned int rrA = rsp[nA];
        const unsigned int rrB = (nB < N_NODES) ? rsp[nB] : 0u;
        const int e0A = (int)(rrA & 0xFFFFu), e1A = (int)(rrA >> 16);
        const int e0B = (int)(rrB & 0xFFFFu), e1B = (int)(rrB >> 16);
        int kA = e0A, kB = e0B;
        const int tA = e1A - e0A, tB = e1B - e0B;
        const int trips = (tA > tB ? tA : tB) >> 2;
        float sA0 = 0.f, sA1 = 0.f, sA2 = 0.f, sA3 = 0.f;
        float sB0 = 0.f, sB1 = 0.f, sB2 = 0.f, sB3 = 0.f;
        #pragma unroll 2
        for (int t = 0; t < trips; ++t) {
            // wave-uniform clamp: exhausted side re-reads its own start, w -> 0
            const unsigned int pA = ebs[((kA < e1A) ? kA : e0A) + h];
            const unsigned int pB = ebs[((kB < e1B) ? kB : e0B) + h];
            const unsigned int wmA = (kA < e1A) ? 0xFFFF0000u : 0u;
            const unsigned int wmB = (kB < e1B) ? 0xFFFF0000u : 0u;
            const uint2 xvA = *(const uint2*)(xsb + ((pA & 0xFFFFu) | li8));
            const uint2 xvB = *(const uint2*)(xsb + ((pB & 0xFFFFu) | li8));
            const unsigned int wA = pA & wmA;
            const unsigned int wB = pB & wmB;
            sA0 = fmaf(uf(wA), uf(xvA.x << 16),         sA0);
            sA1 = fmaf(uf(wA), uf(xvA.x & 0xFFFF0000u), sA1);
            sA2 = fmaf(uf(wA), uf(xvA.y << 16),         sA2);
            sA3 = fmaf(uf(wA), uf(xvA.y & 0xFFFF0000u), sA3);
            sB0 = fmaf(uf(wB), uf(xvB.x << 16),         sB0);
            sB1 = fmaf(uf(wB), uf(xvB.x & 0xFFFF0000u), sB1);
            sB2 = fmaf(uf(wB), uf(xvB.y << 16),         sB2);
            sB3 = fmaf(uf(wB), uf(xvB.y & 0xFFFF0000u), sB3);
            kA += 4; kB += 4;
        }
        // combine the 4 quads' partials; afterwards ALL lanes hold the totals
        sA0 += __shfl_xor(sA0, 16); sA1 += __shfl_xor(sA1, 16);
        sA2 += __shfl_xor(sA2, 16); sA3 += __shfl_xor(sA3, 16);
        sB0 += __shfl_xor(sB0, 16); sB1 += __shfl_xor(sB1, 16);
        sB2 += __shfl_xor(sB2, 16); sB3 += __shfl_xor(sB3, 16);
        sA0 += __shfl_xor(sA0, 32); sA1 += __shfl_xor(sA1, 32);
        sA2 += __shfl_xor(sA2, 32); sA3 += __shfl_xor(sA3, 32);
        sB0 += __shfl_xor(sB0, 32); sB1 += __shfl_xor(sB1, 32);
        sB2 += __shfl_xor(sB2, 32); sB3 += __shfl_xor(sB3, 32);
        // paired epilogue: lanes 0-15 -> row nA, lanes 16-31 -> row nB
        if (lane < 32) {
            const bool isB = (lane >= 16);
            const int n = isB ? nB : nA;
            if (n < N_NODES) {
                const float r0 = isB ? sB0 : sA0;
                const float r1 = isB ? sB1 : sA1;
                const float r2 = isB ? sB2 : sA2;
                const float r3 = isB ? sB3 : sA3;
                const float2 cb = cbs[n];
                const int o4 = (n << 6) + ((lane & 15) << 2);
                const float4 xg = *(const float4*)(xb + o4);   // fp32 self term
                float4 o;
                o.x = fmaf(cb.x, xg.x, cb.y) - r0;
                o.y = fmaf(cb.x, xg.y, cb.y) - r1;
                o.z = fmaf(cb.x, xg.z, cb.y) - r2;
                o.w = fmaf(cb.x, xg.w, cb.y) - r3;
                *(float4*)(ob + o4) = o;
            }
        }
    }
}

// ---------------------------------------------------------------------------
// K2 (fallback, baseline-style, padded-CSR aware): used only if ws too small
// for the eb32p table. Per-block weight gather + u16 LDS reads.
// ---------------------------------------------------------------------------
__global__ __launch_bounds__(512, 8) void diffusion_gcn_fallback(
    const float* __restrict__ inputs,
    const float* __restrict__ weight_diff,
    const int*   __restrict__ ind,
    const int*   __restrict__ rs_p_g,
    const unsigned int* __restrict__ csr_p,
    const float2* __restrict__ coefbias,
    float* __restrict__ out) {
    __shared__ unsigned short xsh[N_NODES * L_DIM];
    __shared__ unsigned int   wnb[EB_STRIDE];
    __shared__ unsigned short rs[N_NODES + 1];

    const int b    = blockIdx.x;
    const int tid  = threadIdx.x;
    const int slot = ind[b];

    const float* xb = inputs + (size_t)b * (2 * N_NODES * L_DIM);

    const float4* xb4 = (const float4*)xb;
    for (int k = tid; k < (N_NODES * L_DIM) / 4; k += 512) {
        const float4 v = xb4[k];
        const unsigned int lo = (f2bf_rtn_bits_hi(v.x) >> 16) | f2bf_rtn_bits_hi(v.y);
        const unsigned int hi = (f2bf_rtn_bits_hi(v.z) >> 16) | f2bf_rtn_bits_hi(v.w);
        ((uint2*)xsh)[k] = make_uint2(lo, hi);
    }
    const int EP = rs_p_g[N_NODES];
    const float* wrow = weight_diff + (size_t)slot * N_EDGES;
    for (int k = tid; k < EP; k += 512) {
        const unsigned int c = csr_p[k];
        wnb[k] = (c == 0xFFFFFFFFu) ? 0u
                                    : (f2bf_rtn_bits_hi(wrow[c >> 8]) | (c & 255u));
    }
    for (int n = tid; n <= N_NODES; n += 512) rs[n] = (unsigned short)rs_p_g[n];
    __syncthreads();

    const int lane = tid & 63;
    const int wv   = tid >> 6;
    float* ob = out + (size_t)b * (N_NODES * L_DIM);

    for (int n = wv; n < N_NODES; n += 8) {
        const int e0 = rs[n], e1 = rs[n + 1];
        float s = 0.f;
        #pragma unroll 4
        for (int k = e0; k < e1; ++k) {
            const unsigned int p = wnb[k];
            const float w  = __uint_as_float(p & 0xFFFF0000u);
            const float xv = __uint_as_float(
                (unsigned int)xsh[(p & 255u) * L_DIM + lane] << 16);
            s = fmaf(w, xv, s);
        }
        const float2 cb = coefbias[slot * N_NODES + n];
        const float  xg = xb[n * L_DIM + lane];
        ob[n * L_DIM + lane] = fmaf(cb.x, xg, cb.y) - s;
    }
}

extern "C" void kernel_launch(void* const* d_in, const int* in_sizes, int n_in,
                              void* d_out, int out_size, void* d_ws, size_t ws_size,
                              hipStream_t stream) {
    const float* inputs           = (const float*)d_in[0];
    const float* weight_diff      = (const float*)d_in[1];
    const float* bias_diffusion   = (const float*)d_in[2];
    const float* weight_self_loop = (const float*)d_in[3];
    const int*   ind              = (const int*)d_in[4];
    const int*   edge_i           = (const int*)d_in[5];
    const int*   edge_j           = (const int*)d_in[6];
    float* out = (float*)d_out;

    const int B = in_sizes[4];                 // 1024

    // ws layout
    char* ws = (char*)d_ws;
    int*          rs_p     = (int*)ws;                           //      1,024 B
    unsigned int* csr_p    = (unsigned int*)(ws + 1024);         //     16,384 B
    float2*       coefbias = (float2*)(ws + 17408);              //    476,928 B
    unsigned int* eb32p    = (unsigned int*)(ws + 494336);       //  4,718,592 B
    const size_t WS_FULL = 494336 + (size_t)N_SLOTS * EB_STRIDE * sizeof(unsigned int);

    const bool full = (d_ws != nullptr) && (ws_size >= WS_FULL);

    build_csr_kernel<<<1, 256, 0, stream>>>(edge_i, edge_j, rs_p, csr_p);
    coef_eb_kernel<<<N_SLOTS, 256, 0, stream>>>(
        weight_diff, bias_diffusion, weight_self_loop, rs_p, csr_p,
        coefbias, full ? eb32p : nullptr);
    if (full) {
        diffusion_dual_kernel<<<B, 512, 0, stream>>>(
            inputs, ind, rs_p, eb32p, coefbias, out);
    } else {
        diffusion_gcn_fallback<<<B, 512, 0, stream>>>(
            inputs, weight_diff, ind, rs_p, csr_p, coefbias, out);
    }
}